// Round 2
// baseline (231.506 us; speedup 1.0000x reference)
//
#include <hip/hip_runtime.h>
#include <hip/hip_bf16.h>

typedef short bf16x8 __attribute__((ext_vector_type(8)));
typedef float f32x4  __attribute__((ext_vector_type(4)));
typedef float f32x16 __attribute__((ext_vector_type(16)));

__device__ inline short f2bf(float f) {
    __hip_bfloat16 h = __float2bfloat16(f);
    return *reinterpret_cast<short*>(&h);
}
__device__ inline float bf2f(short s) {
    union { unsigned u; float f; } x;
    x.u = (unsigned)(unsigned short)s << 16;
    return x.f;
}

// ------- fused pre-pass: P = src_h @ W1[:128] + b1, Q = dst_h @ W1[128:] ----
// One block = one 128-node tile of ONE table (tb = blockIdx & 1).
// Block converts its own W1-half f32->bf16 directly into 32 KB swizzled LDS
// (W1 is 128 KB, L2/L3-resident after the first wave of blocks).
__global__ void __launch_bounds__(256) precompute_pq(
    const float* __restrict__ W1, const float* __restrict__ b1,
    const float* __restrict__ src_h, const float* __restrict__ dst_h,
    short* __restrict__ P, short* __restrict__ Q,
    int n_nodes, int n_tiles)
{
    __shared__ short sW[128 * 128];   // 32 KB: [col][16 chunks of 16B], XOR-swizzled

    const int bb  = blockIdx.x;
    const int tb  = bb & 1;           // 0 = src/P, 1 = dst/Q
    const int t   = bb >> 1;
    const int tid = threadIdx.x;

    {   // fill: thread -> (col cc, k-half kh); chunk ci covers k = ci*8..ci*8+7
        int cc = tid & 127, kh = tid >> 7;
        const int sw = (cc & 15) << 4;
        char* dbase = reinterpret_cast<char*>(sW) + cc * 256;
        #pragma unroll
        for (int ch = 0; ch < 8; ++ch) {
            int ci = kh * 8 + ch;
            bf16x8 v;
            #pragma unroll
            for (int j = 0; j < 8; ++j)
                v[j] = f2bf(W1[(size_t)(tb * 128 + ci * 8 + j) * 128 + cc]);
            *reinterpret_cast<bf16x8*>(dbase + ((ci * 16) ^ sw)) = v;
        }
    }
    __syncthreads();

    const int lane = tid & 63;
    const int wv   = tid >> 6;
    const int l31  = lane & 31;
    const int hg   = lane >> 5;

    const int nodeBase = t * 128 + wv * 32;
    if (nodeBase >= n_nodes) return;          // after the barrier: safe
    int nl = nodeBase + l31; if (nl >= n_nodes) nl = n_nodes - 1;

    const float* x = (tb ? dst_h : src_h) + (size_t)nl * 128 + hg * 8;

    f32x16 acc[4];
    #pragma unroll
    for (int nf = 0; nf < 4; ++nf) acc[nf] = (f32x16)(0.0f);

    #pragma unroll
    for (int kk = 0; kk < 8; ++kk) {
        f32x4 u = *reinterpret_cast<const f32x4*>(x + kk * 16);
        f32x4 v = *reinterpret_cast<const f32x4*>(x + kk * 16 + 4);
        bf16x8 a;
        #pragma unroll
        for (int j = 0; j < 4; ++j) { a[j] = f2bf(u[j]); a[4 + j] = f2bf(v[j]); }
        #pragma unroll
        for (int nf = 0; nf < 4; ++nf) {
            int col = nf * 32 + l31;
            const char* bp = reinterpret_cast<const char*>(sW)
                + col * 256 + ((kk * 32 + hg * 16) ^ ((col & 15) << 4));
            bf16x8 bfr = *reinterpret_cast<const bf16x8*>(bp);
            acc[nf] = __builtin_amdgcn_mfma_f32_32x32x16_bf16(a, bfr, acc[nf], 0, 0, 0);
        }
    }

    short* T = tb ? Q : P;
    #pragma unroll
    for (int nf = 0; nf < 4; ++nf) {
        int col = nf * 32 + l31;
        float b1v = tb ? 0.0f : b1[col];      // fold b1 into P
        #pragma unroll
        for (int rg = 0; rg < 16; ++rg) {
            int row  = (rg & 3) + 8 * (rg >> 2) + 4 * hg;
            int node = nodeBase + row;
            if (node < n_nodes)
                T[(size_t)node * 128 + col] = f2bf(acc[nf][rg] + b1v);
        }
    }
}

// ------- main: pure gather + elementwise.  16 lanes per node-row.
// Wave batch = 64 edges (4 iters x 16 edges, slots i=0..3, group g=lane>>4).
// Double-buffered row loads, idx prefetched 2 iters ahead, dense 512B stores.
__global__ void __launch_bounds__(256, 8) edge_score(
    const short* __restrict__ P, const short* __restrict__ Q,
    const int* __restrict__ src_idx, const int* __restrict__ dst_idx,
    const float* __restrict__ W2, const float* __restrict__ b2,
    float* __restrict__ out, int n_edges, int n_batches)
{
    __shared__ float sOut[4][128];       // per-wave 64 x float2 bounce

    const int tid  = threadIdx.x;
    const int wv   = tid >> 6;
    const int lane = tid & 63;
    const int g    = lane >> 4;          // 0..3  : edge slot-within-quad
    const int c    = lane & 15;          // 0..15 : 8-feature chunk of the row

    float* sOutW = &sOut[wv][0];

    // per-lane constants: this lane's 8 feature channels (b1 folded into P)
    float wdf[8];
    #pragma unroll
    for (int j = 0; j < 8; ++j) {
        int k = c * 8 + j;
        wdf[j] = W2[k * 2 + 1] - W2[k * 2 + 0];   // w2[:,1]-w2[:,0]
    }
    const float cdiff = b2[1] - b2[0];

    const int gw = blockIdx.x * 4 + wv;
    const int nw = gridDim.x * 4;

    for (int b = gw; b < n_batches; b += nw) {
        const int ebase = b << 6;

        int    is_[2][4], id_[2][4];
        bf16x8 pv_[2][4], qv_[2][4];

        // prologue: idx(0) -> rows(0) -> idx(1)
        #pragma unroll
        for (int i = 0; i < 4; ++i) {
            int e = ebase + i * 4 + g; if (e >= n_edges) e = n_edges - 1;
            is_[0][i] = src_idx[e]; id_[0][i] = dst_idx[e];
        }
        #pragma unroll
        for (int i = 0; i < 4; ++i) {
            pv_[0][i] = *reinterpret_cast<const bf16x8*>(P + (size_t)is_[0][i] * 128 + c * 8);
            qv_[0][i] = *reinterpret_cast<const bf16x8*>(Q + (size_t)id_[0][i] * 128 + c * 8);
        }
        #pragma unroll
        for (int i = 0; i < 4; ++i) {
            int e = ebase + 16 + i * 4 + g; if (e >= n_edges) e = n_edges - 1;
            is_[1][i] = src_idx[e]; id_[1][i] = dst_idx[e];
        }

        #pragma unroll
        for (int n = 0; n < 4; ++n) {
            const int cur = n & 1, nxt = cur ^ 1;

            // issue rows(n+1) from idx(n+1)
            if (n < 3) {
                #pragma unroll
                for (int i = 0; i < 4; ++i) {
                    pv_[nxt][i] = *reinterpret_cast<const bf16x8*>(P + (size_t)is_[nxt][i] * 128 + c * 8);
                    qv_[nxt][i] = *reinterpret_cast<const bf16x8*>(Q + (size_t)id_[nxt][i] * 128 + c * 8);
                }
            }
            // prefetch idx(n+2) into the just-freed slot
            if (n < 2) {
                #pragma unroll
                for (int i = 0; i < 4; ++i) {
                    int e = ebase + (n + 2) * 16 + i * 4 + g; if (e >= n_edges) e = n_edges - 1;
                    is_[cur][i] = src_idx[e]; id_[cur][i] = dst_idx[e];
                }
            }
            // compute(n)
            #pragma unroll
            for (int i = 0; i < 4; ++i) {
                float a = 0.f;
                #pragma unroll
                for (int j = 0; j < 8; ++j) {
                    float h = fmaxf(bf2f(pv_[cur][i][j]) + bf2f(qv_[cur][i][j]), 0.f);
                    a = fmaf(h, wdf[j], a);
                }
                a += __shfl_xor(a, 1);
                a += __shfl_xor(a, 2);
                a += __shfl_xor(a, 4);
                a += __shfl_xor(a, 8);
                if (c == i) {
                    float D  = a + cdiff;                      // z1 - z0
                    float p0 = 1.0f / (1.0f + __expf(D));
                    reinterpret_cast<float2*>(sOutW)[n * 16 + i * 4 + g] =
                        make_float2(p0, 1.0f - p0);
                }
            }
        }

        // dense full-wave store: 64 lanes x float2 = 512B contiguous
        asm volatile("s_waitcnt lgkmcnt(0)" ::: "memory");
        {
            float2 r = reinterpret_cast<float2*>(sOutW)[lane];
            int e = ebase + lane;
            if (e < n_edges)
                *reinterpret_cast<float2*>(out + (size_t)e * 2) = r;
        }
    }
}

// ------- fallback (ws too small; not expected to run) -------
__global__ void __launch_bounds__(256) edge_naive(
    const float* __restrict__ src_h, const float* __restrict__ dst_h,
    const int* __restrict__ src_idx, const int* __restrict__ dst_idx,
    const float* __restrict__ W1, const float* __restrict__ b1,
    const float* __restrict__ W2, const float* __restrict__ b2,
    float* __restrict__ out, int n_edges)
{
    int e = blockIdx.x * 256 + threadIdx.x;
    if (e >= n_edges) return;
    const float* xs = src_h + (size_t)src_idx[e] * 128;
    const float* xd = dst_h + (size_t)dst_idx[e] * 128;
    float z0 = b2[0], z1 = b2[1];
    for (int j = 0; j < 128; ++j) {
        float s = b1[j];
        for (int k = 0; k < 128; ++k) s += xs[k] * W1[k * 128 + j];
        for (int k = 0; k < 128; ++k) s += xd[k] * W1[(128 + k) * 128 + j];
        float h = fmaxf(s, 0.f);
        z0 = fmaf(h, W2[j * 2], z0);
        z1 = fmaf(h, W2[j * 2 + 1], z1);
    }
    float p0 = 1.f / (1.f + __expf(z1 - z0));
    out[(size_t)e * 2] = p0; out[(size_t)e * 2 + 1] = 1.f - p0;
}

extern "C" void kernel_launch(void* const* d_in, const int* in_sizes, int n_in,
                              void* d_out, int out_size, void* d_ws, size_t ws_size,
                              hipStream_t stream) {
    const float* src_h   = (const float*)d_in[0];
    const float* dst_h   = (const float*)d_in[1];
    const int*   src_idx = (const int*)d_in[2];
    const int*   dst_idx = (const int*)d_in[3];
    const float* W1      = (const float*)d_in[4];
    const float* b1      = (const float*)d_in[5];
    const float* W2      = (const float*)d_in[6];
    const float* b2      = (const float*)d_in[7];
    float* out = (float*)d_out;

    int n_nodes = in_sizes[0] / 128;
    int n_edges = in_sizes[2];

    size_t need = (size_t)n_nodes * 256 * sizeof(short);     // P + Q
    bool use_bf16 = (ws_size >= need);

    if (use_bf16) {
        short* ws = (short*)d_ws;
        short* Pp = ws;
        short* Qp = ws + (size_t)n_nodes * 128;

        int n_tiles = (n_nodes + 127) / 128;
        hipLaunchKernelGGL(precompute_pq, dim3(2 * n_tiles), dim3(256), 0, stream,
                           W1, b1, src_h, dst_h, Pp, Qp, n_nodes, n_tiles);

        int n_batches = (n_edges + 63) / 64;
        int grid = n_batches < 2048 ? n_batches : 2048;
        hipLaunchKernelGGL(edge_score, dim3(grid), dim3(256), 0, stream,
                           Pp, Qp, src_idx, dst_idx, W2, b2,
                           out, n_edges, n_batches);
    } else {
        hipLaunchKernelGGL(edge_naive, dim3((n_edges + 255) / 256), dim3(256), 0, stream,
                           src_h, dst_h, src_idx, dst_idx,
                           W1, b1, W2, b2, out, n_edges);
    }
}

// Round 3
// 124.490 us; speedup vs baseline: 1.8596x; 1.8596x over previous
//
#include <hip/hip_runtime.h>
#include <hip/hip_bf16.h>

typedef short bf16x8 __attribute__((ext_vector_type(8)));
typedef float f32x4  __attribute__((ext_vector_type(4)));
typedef float f32x16 __attribute__((ext_vector_type(16)));

__device__ inline short f2bf(float f) {
    __hip_bfloat16 h = __float2bfloat16(f);
    return *reinterpret_cast<short*>(&h);
}
__device__ inline float bf2f(short s) {
    union { unsigned u; float f; } x;
    x.u = (unsigned)(unsigned short)s << 16;
    return x.f;
}

// ------- fused pre-pass: P = src_h @ W1[:128] + b1, Q = dst_h @ W1[128:] ----
// One block = one 128-node tile of ONE table (tb = blockIdx & 1).
// Block converts its own W1-half f32->bf16 directly into 32 KB swizzled LDS
// (W1 is 128 KB, L2/L3-resident after the first wave of blocks).
__global__ void __launch_bounds__(256) precompute_pq(
    const float* __restrict__ W1, const float* __restrict__ b1,
    const float* __restrict__ src_h, const float* __restrict__ dst_h,
    short* __restrict__ P, short* __restrict__ Q,
    int n_nodes, int n_tiles)
{
    __shared__ short sW[128 * 128];   // 32 KB: [col][16 chunks of 16B], XOR-swizzled

    const int bb  = blockIdx.x;
    const int tb  = bb & 1;           // 0 = src/P, 1 = dst/Q
    const int t   = bb >> 1;
    const int tid = threadIdx.x;

    {   // fill: thread -> (col cc, k-half kh); chunk ci covers k = ci*8..ci*8+7
        int cc = tid & 127, kh = tid >> 7;
        const int sw = (cc & 15) << 4;
        char* dbase = reinterpret_cast<char*>(sW) + cc * 256;
        #pragma unroll
        for (int ch = 0; ch < 8; ++ch) {
            int ci = kh * 8 + ch;
            bf16x8 v;
            #pragma unroll
            for (int j = 0; j < 8; ++j)
                v[j] = f2bf(W1[(size_t)(tb * 128 + ci * 8 + j) * 128 + cc]);
            *reinterpret_cast<bf16x8*>(dbase + ((ci * 16) ^ sw)) = v;
        }
    }
    __syncthreads();

    const int lane = tid & 63;
    const int wv   = tid >> 6;
    const int l31  = lane & 31;
    const int hg   = lane >> 5;

    const int nodeBase = t * 128 + wv * 32;
    if (nodeBase >= n_nodes) return;          // after the barrier: safe
    int nl = nodeBase + l31; if (nl >= n_nodes) nl = n_nodes - 1;

    const float* x = (tb ? dst_h : src_h) + (size_t)nl * 128 + hg * 8;

    f32x16 acc[4];
    #pragma unroll
    for (int nf = 0; nf < 4; ++nf) acc[nf] = (f32x16)(0.0f);

    #pragma unroll
    for (int kk = 0; kk < 8; ++kk) {
        f32x4 u = *reinterpret_cast<const f32x4*>(x + kk * 16);
        f32x4 v = *reinterpret_cast<const f32x4*>(x + kk * 16 + 4);
        bf16x8 a;
        #pragma unroll
        for (int j = 0; j < 4; ++j) { a[j] = f2bf(u[j]); a[4 + j] = f2bf(v[j]); }
        #pragma unroll
        for (int nf = 0; nf < 4; ++nf) {
            int col = nf * 32 + l31;
            const char* bp = reinterpret_cast<const char*>(sW)
                + col * 256 + ((kk * 32 + hg * 16) ^ ((col & 15) << 4));
            bf16x8 bfr = *reinterpret_cast<const bf16x8*>(bp);
            acc[nf] = __builtin_amdgcn_mfma_f32_32x32x16_bf16(a, bfr, acc[nf], 0, 0, 0);
        }
    }

    short* T = tb ? Q : P;
    #pragma unroll
    for (int nf = 0; nf < 4; ++nf) {
        int col = nf * 32 + l31;
        float b1v = tb ? 0.0f : b1[col];      // fold b1 into P
        #pragma unroll
        for (int rg = 0; rg < 16; ++rg) {
            int row  = (rg & 3) + 8 * (rg >> 2) + 4 * hg;
            int node = nodeBase + row;
            if (node < n_nodes)
                T[(size_t)node * 128 + col] = f2bf(acc[nf][rg] + b1v);
        }
    }
}

// ------- main: pure gather + elementwise.  16 lanes per node-row.
// Wave batch = 64 edges (4 iters x 16 edges, slots i=0..3, group g=lane>>4).
// Double-buffered row loads, idx prefetched 2 iters ahead, dense 512B stores.
// NOTE: min-waves hint stays at 4. VGPR=60 <= 64 already allows 8 blocks/CU;
// forcing 8 squeezed VGPR to 32 and spilled the pipeline state to scratch
// (round-2 post-mortem: WRITE_SIZE 7.8 -> 209 MB, dur 79.5 -> 186 us).
__global__ void __launch_bounds__(256, 4) edge_score(
    const short* __restrict__ P, const short* __restrict__ Q,
    const int* __restrict__ src_idx, const int* __restrict__ dst_idx,
    const float* __restrict__ W2, const float* __restrict__ b2,
    float* __restrict__ out, int n_edges, int n_batches)
{
    __shared__ float sOut[4][128];       // per-wave 64 x float2 bounce

    const int tid  = threadIdx.x;
    const int wv   = tid >> 6;
    const int lane = tid & 63;
    const int g    = lane >> 4;          // 0..3  : edge slot-within-quad
    const int c    = lane & 15;          // 0..15 : 8-feature chunk of the row

    float* sOutW = &sOut[wv][0];

    // per-lane constants: this lane's 8 feature channels (b1 folded into P)
    float wdf[8];
    #pragma unroll
    for (int j = 0; j < 8; ++j) {
        int k = c * 8 + j;
        wdf[j] = W2[k * 2 + 1] - W2[k * 2 + 0];   // w2[:,1]-w2[:,0]
    }
    const float cdiff = b2[1] - b2[0];

    const int gw = blockIdx.x * 4 + wv;
    const int nw = gridDim.x * 4;

    for (int b = gw; b < n_batches; b += nw) {
        const int ebase = b << 6;

        int    is_[2][4], id_[2][4];
        bf16x8 pv_[2][4], qv_[2][4];

        // prologue: idx(0) -> rows(0) -> idx(1)
        #pragma unroll
        for (int i = 0; i < 4; ++i) {
            int e = ebase + i * 4 + g; if (e >= n_edges) e = n_edges - 1;
            is_[0][i] = src_idx[e]; id_[0][i] = dst_idx[e];
        }
        #pragma unroll
        for (int i = 0; i < 4; ++i) {
            pv_[0][i] = *reinterpret_cast<const bf16x8*>(P + (size_t)is_[0][i] * 128 + c * 8);
            qv_[0][i] = *reinterpret_cast<const bf16x8*>(Q + (size_t)id_[0][i] * 128 + c * 8);
        }
        #pragma unroll
        for (int i = 0; i < 4; ++i) {
            int e = ebase + 16 + i * 4 + g; if (e >= n_edges) e = n_edges - 1;
            is_[1][i] = src_idx[e]; id_[1][i] = dst_idx[e];
        }

        #pragma unroll
        for (int n = 0; n < 4; ++n) {
            const int cur = n & 1, nxt = cur ^ 1;

            // issue rows(n+1) from idx(n+1)
            if (n < 3) {
                #pragma unroll
                for (int i = 0; i < 4; ++i) {
                    pv_[nxt][i] = *reinterpret_cast<const bf16x8*>(P + (size_t)is_[nxt][i] * 128 + c * 8);
                    qv_[nxt][i] = *reinterpret_cast<const bf16x8*>(Q + (size_t)id_[nxt][i] * 128 + c * 8);
                }
            }
            // prefetch idx(n+2) into the just-freed slot
            if (n < 2) {
                #pragma unroll
                for (int i = 0; i < 4; ++i) {
                    int e = ebase + (n + 2) * 16 + i * 4 + g; if (e >= n_edges) e = n_edges - 1;
                    is_[cur][i] = src_idx[e]; id_[cur][i] = dst_idx[e];
                }
            }
            // compute(n)
            #pragma unroll
            for (int i = 0; i < 4; ++i) {
                float a = 0.f;
                #pragma unroll
                for (int j = 0; j < 8; ++j) {
                    float h = fmaxf(bf2f(pv_[cur][i][j]) + bf2f(qv_[cur][i][j]), 0.f);
                    a = fmaf(h, wdf[j], a);
                }
                a += __shfl_xor(a, 1);
                a += __shfl_xor(a, 2);
                a += __shfl_xor(a, 4);
                a += __shfl_xor(a, 8);
                if (c == i) {
                    float D  = a + cdiff;                      // z1 - z0
                    float p0 = 1.0f / (1.0f + __expf(D));
                    reinterpret_cast<float2*>(sOutW)[n * 16 + i * 4 + g] =
                        make_float2(p0, 1.0f - p0);
                }
            }
        }

        // dense full-wave store: 64 lanes x float2 = 512B contiguous
        asm volatile("s_waitcnt lgkmcnt(0)" ::: "memory");
        {
            float2 r = reinterpret_cast<float2*>(sOutW)[lane];
            int e = ebase + lane;
            if (e < n_edges)
                *reinterpret_cast<float2*>(out + (size_t)e * 2) = r;
        }
    }
}

// ------- fallback (ws too small; not expected to run) -------
__global__ void __launch_bounds__(256) edge_naive(
    const float* __restrict__ src_h, const float* __restrict__ dst_h,
    const int* __restrict__ src_idx, const int* __restrict__ dst_idx,
    const float* __restrict__ W1, const float* __restrict__ b1,
    const float* __restrict__ W2, const float* __restrict__ b2,
    float* __restrict__ out, int n_edges)
{
    int e = blockIdx.x * 256 + threadIdx.x;
    if (e >= n_edges) return;
    const float* xs = src_h + (size_t)src_idx[e] * 128;
    const float* xd = dst_h + (size_t)dst_idx[e] * 128;
    float z0 = b2[0], z1 = b2[1];
    for (int j = 0; j < 128; ++j) {
        float s = b1[j];
        for (int k = 0; k < 128; ++k) s += xs[k] * W1[k * 128 + j];
        for (int k = 0; k < 128; ++k) s += xd[k] * W1[(128 + k) * 128 + j];
        float h = fmaxf(s, 0.f);
        z0 = fmaf(h, W2[j * 2], z0);
        z1 = fmaf(h, W2[j * 2 + 1], z1);
    }
    float p0 = 1.f / (1.f + __expf(z1 - z0));
    out[(size_t)e * 2] = p0; out[(size_t)e * 2 + 1] = 1.f - p0;
}

extern "C" void kernel_launch(void* const* d_in, const int* in_sizes, int n_in,
                              void* d_out, int out_size, void* d_ws, size_t ws_size,
                              hipStream_t stream) {
    const float* src_h   = (const float*)d_in[0];
    const float* dst_h   = (const float*)d_in[1];
    const int*   src_idx = (const int*)d_in[2];
    const int*   dst_idx = (const int*)d_in[3];
    const float* W1      = (const float*)d_in[4];
    const float* b1      = (const float*)d_in[5];
    const float* W2      = (const float*)d_in[6];
    const float* b2      = (const float*)d_in[7];
    float* out = (float*)d_out;

    int n_nodes = in_sizes[0] / 128;
    int n_edges = in_sizes[2];

    size_t need = (size_t)n_nodes * 256 * sizeof(short);     // P + Q
    bool use_bf16 = (ws_size >= need);

    if (use_bf16) {
        short* ws = (short*)d_ws;
        short* Pp = ws;
        short* Qp = ws + (size_t)n_nodes * 128;

        int n_tiles = (n_nodes + 127) / 128;
        hipLaunchKernelGGL(precompute_pq, dim3(2 * n_tiles), dim3(256), 0, stream,
                           W1, b1, src_h, dst_h, Pp, Qp, n_nodes, n_tiles);

        int n_batches = (n_edges + 63) / 64;
        int grid = n_batches < 2048 ? n_batches : 2048;
        hipLaunchKernelGGL(edge_score, dim3(grid), dim3(256), 0, stream,
                           Pp, Qp, src_idx, dst_idx, W2, b2,
                           out, n_edges, n_batches);
    } else {
        hipLaunchKernelGGL(edge_naive, dim3((n_edges + 255) / 256), dim3(256), 0, stream,
                           src_h, dst_h, src_idx, dst_idx,
                           W1, b1, W2, b2, out, n_edges);
    }
}

// Round 4
// 123.166 us; speedup vs baseline: 1.8796x; 1.0107x over previous
//
#include <hip/hip_runtime.h>
#include <hip/hip_bf16.h>

typedef short bf16x8 __attribute__((ext_vector_type(8)));
typedef float f32x4  __attribute__((ext_vector_type(4)));
typedef float f32x16 __attribute__((ext_vector_type(16)));

__device__ inline short f2bf(float f) {
    __hip_bfloat16 h = __float2bfloat16(f);
    return *reinterpret_cast<short*>(&h);
}
__device__ inline float bf2f(short s) {
    union { unsigned u; float f; } x;
    x.u = (unsigned)(unsigned short)s << 16;
    return x.f;
}

// ------- pre-pass 1: W1 [256,128] f32 -> w1t_sw: two 32 KB halves, each in
// the EXACT swizzled LDS image precompute_pq uses ([col][chunk], byte
// offset cc*256 + ((ci*16) ^ ((cc&15)<<4))). One-time cost; lets every
// precompute block fill its LDS with 8 coalesced b128 copies per thread
// instead of 64 strided scalar loads (round-3 regression: +12 us).
__global__ void __launch_bounds__(256) convert_w1(
    const float* __restrict__ W1, short* __restrict__ w1t_sw)
{
    int i = blockIdx.x * 256 + threadIdx.x;   // 4096 threads: (H, cc, ci)
    int H  = i >> 11;
    int r  = i & 2047;
    int cc = r >> 4, ci = r & 15;
    bf16x8 v;
    #pragma unroll
    for (int j = 0; j < 8; ++j)
        v[j] = f2bf(W1[(size_t)(H * 128 + ci * 8 + j) * 128 + cc]);
    char* base = reinterpret_cast<char*>(w1t_sw) + H * 32768;
    *reinterpret_cast<bf16x8*>(base + cc * 256 + ((ci * 16) ^ ((cc & 15) << 4))) = v;
}

// ------- pre-pass 2: P = src_h @ W1[:128] + b1, Q = dst_h @ W1[128:] ----
// One block = one 128-node tile of ONE table (tb = blockIdx & 1).
// LDS fill = linear 32 KB memcpy of the pre-swizzled W1-half image (L2-hot).
__global__ void __launch_bounds__(256) precompute_pq(
    const short* __restrict__ w1t_sw, const float* __restrict__ b1,
    const float* __restrict__ src_h, const float* __restrict__ dst_h,
    short* __restrict__ P, short* __restrict__ Q,
    int n_nodes, int n_tiles)
{
    __shared__ short sW[128 * 128];   // 32 KB: [col][16 chunks of 16B], XOR-swizzled

    const int bb  = blockIdx.x;
    const int tb  = bb & 1;           // 0 = src/P, 1 = dst/Q
    const int t   = bb >> 1;
    const int tid = threadIdx.x;

    {   // fill: straight copy, 8 x b128 per thread, fully coalesced
        const short* src = w1t_sw + tb * 16384;
        #pragma unroll
        for (int ch = 0; ch < 8; ++ch) {
            int g = ch * 256 + tid;           // 0..2047 16B-chunks
            *reinterpret_cast<bf16x8*>(sW + (size_t)g * 8) =
                *reinterpret_cast<const bf16x8*>(src + (size_t)g * 8);
        }
    }
    __syncthreads();

    const int lane = tid & 63;
    const int wv   = tid >> 6;
    const int l31  = lane & 31;
    const int hg   = lane >> 5;

    const int nodeBase = t * 128 + wv * 32;
    if (nodeBase >= n_nodes) return;          // after the barrier: safe
    int nl = nodeBase + l31; if (nl >= n_nodes) nl = n_nodes - 1;

    const float* x = (tb ? dst_h : src_h) + (size_t)nl * 128 + hg * 8;

    f32x16 acc[4];
    #pragma unroll
    for (int nf = 0; nf < 4; ++nf) acc[nf] = (f32x16)(0.0f);

    #pragma unroll
    for (int kk = 0; kk < 8; ++kk) {
        f32x4 u = *reinterpret_cast<const f32x4*>(x + kk * 16);
        f32x4 v = *reinterpret_cast<const f32x4*>(x + kk * 16 + 4);
        bf16x8 a;
        #pragma unroll
        for (int j = 0; j < 4; ++j) { a[j] = f2bf(u[j]); a[4 + j] = f2bf(v[j]); }
        #pragma unroll
        for (int nf = 0; nf < 4; ++nf) {
            int col = nf * 32 + l31;
            const char* bp = reinterpret_cast<const char*>(sW)
                + col * 256 + ((kk * 32 + hg * 16) ^ ((col & 15) << 4));
            bf16x8 bfr = *reinterpret_cast<const bf16x8*>(bp);
            acc[nf] = __builtin_amdgcn_mfma_f32_32x32x16_bf16(a, bfr, acc[nf], 0, 0, 0);
        }
    }

    short* T = tb ? Q : P;
    #pragma unroll
    for (int nf = 0; nf < 4; ++nf) {
        int col = nf * 32 + l31;
        float b1v = tb ? 0.0f : b1[col];      // fold b1 into P
        #pragma unroll
        for (int rg = 0; rg < 16; ++rg) {
            int row  = (rg & 3) + 8 * (rg >> 2) + 4 * hg;
            int node = nodeBase + row;
            if (node < n_nodes)
                T[(size_t)node * 128 + col] = f2bf(acc[nf][rg] + b1v);
        }
    }
}

// ------- main: pure gather + elementwise.  16 lanes per node-row.
// Wave batch = 64 edges (4 iters x 16 edges, slots i=0..3, group g=lane>>4).
// Double-buffered row loads, idx prefetched 2 iters ahead, dense 512B stores.
// Service-rate bound at ~6.6 TB/s combined L2/L3 random-row service
// (round-3 A/B: 2x occupancy -> +4%). Keep exactly as measured: 76.7 us.
// NOTE: min-waves hint stays at 4. VGPR=60 <= 64 already allows 8 blocks/CU;
// forcing 8 squeezed VGPR to 32 and spilled the pipeline state to scratch
// (round-2 post-mortem: WRITE_SIZE 7.8 -> 209 MB, dur 79.5 -> 186 us).
__global__ void __launch_bounds__(256, 4) edge_score(
    const short* __restrict__ P, const short* __restrict__ Q,
    const int* __restrict__ src_idx, const int* __restrict__ dst_idx,
    const float* __restrict__ W2, const float* __restrict__ b2,
    float* __restrict__ out, int n_edges, int n_batches)
{
    __shared__ float sOut[4][128];       // per-wave 64 x float2 bounce

    const int tid  = threadIdx.x;
    const int wv   = tid >> 6;
    const int lane = tid & 63;
    const int g    = lane >> 4;          // 0..3  : edge slot-within-quad
    const int c    = lane & 15;          // 0..15 : 8-feature chunk of the row

    float* sOutW = &sOut[wv][0];

    // per-lane constants: this lane's 8 feature channels (b1 folded into P)
    float wdf[8];
    #pragma unroll
    for (int j = 0; j < 8; ++j) {
        int k = c * 8 + j;
        wdf[j] = W2[k * 2 + 1] - W2[k * 2 + 0];   // w2[:,1]-w2[:,0]
    }
    const float cdiff = b2[1] - b2[0];

    const int gw = blockIdx.x * 4 + wv;
    const int nw = gridDim.x * 4;

    for (int b = gw; b < n_batches; b += nw) {
        const int ebase = b << 6;

        int    is_[2][4], id_[2][4];
        bf16x8 pv_[2][4], qv_[2][4];

        // prologue: idx(0) -> rows(0) -> idx(1)
        #pragma unroll
        for (int i = 0; i < 4; ++i) {
            int e = ebase + i * 4 + g; if (e >= n_edges) e = n_edges - 1;
            is_[0][i] = src_idx[e]; id_[0][i] = dst_idx[e];
        }
        #pragma unroll
        for (int i = 0; i < 4; ++i) {
            pv_[0][i] = *reinterpret_cast<const bf16x8*>(P + (size_t)is_[0][i] * 128 + c * 8);
            qv_[0][i] = *reinterpret_cast<const bf16x8*>(Q + (size_t)id_[0][i] * 128 + c * 8);
        }
        #pragma unroll
        for (int i = 0; i < 4; ++i) {
            int e = ebase + 16 + i * 4 + g; if (e >= n_edges) e = n_edges - 1;
            is_[1][i] = src_idx[e]; id_[1][i] = dst_idx[e];
        }

        #pragma unroll
        for (int n = 0; n < 4; ++n) {
            const int cur = n & 1, nxt = cur ^ 1;

            // issue rows(n+1) from idx(n+1)
            if (n < 3) {
                #pragma unroll
                for (int i = 0; i < 4; ++i) {
                    pv_[nxt][i] = *reinterpret_cast<const bf16x8*>(P + (size_t)is_[nxt][i] * 128 + c * 8);
                    qv_[nxt][i] = *reinterpret_cast<const bf16x8*>(Q + (size_t)id_[nxt][i] * 128 + c * 8);
                }
            }
            // prefetch idx(n+2) into the just-freed slot
            if (n < 2) {
                #pragma unroll
                for (int i = 0; i < 4; ++i) {
                    int e = ebase + (n + 2) * 16 + i * 4 + g; if (e >= n_edges) e = n_edges - 1;
                    is_[cur][i] = src_idx[e]; id_[cur][i] = dst_idx[e];
                }
            }
            // compute(n)
            #pragma unroll
            for (int i = 0; i < 4; ++i) {
                float a = 0.f;
                #pragma unroll
                for (int j = 0; j < 8; ++j) {
                    float h = fmaxf(bf2f(pv_[cur][i][j]) + bf2f(qv_[cur][i][j]), 0.f);
                    a = fmaf(h, wdf[j], a);
                }
                a += __shfl_xor(a, 1);
                a += __shfl_xor(a, 2);
                a += __shfl_xor(a, 4);
                a += __shfl_xor(a, 8);
                if (c == i) {
                    float D  = a + cdiff;                      // z1 - z0
                    float p0 = 1.0f / (1.0f + __expf(D));
                    reinterpret_cast<float2*>(sOutW)[n * 16 + i * 4 + g] =
                        make_float2(p0, 1.0f - p0);
                }
            }
        }

        // dense full-wave store: 64 lanes x float2 = 512B contiguous
        asm volatile("s_waitcnt lgkmcnt(0)" ::: "memory");
        {
            float2 r = reinterpret_cast<float2*>(sOutW)[lane];
            int e = ebase + lane;
            if (e < n_edges)
                *reinterpret_cast<float2*>(out + (size_t)e * 2) = r;
        }
    }
}

// ------- fallback (ws too small; not expected to run) -------
__global__ void __launch_bounds__(256) edge_naive(
    const float* __restrict__ src_h, const float* __restrict__ dst_h,
    const int* __restrict__ src_idx, const int* __restrict__ dst_idx,
    const float* __restrict__ W1, const float* __restrict__ b1,
    const float* __restrict__ W2, const float* __restrict__ b2,
    float* __restrict__ out, int n_edges)
{
    int e = blockIdx.x * 256 + threadIdx.x;
    if (e >= n_edges) return;
    const float* xs = src_h + (size_t)src_idx[e] * 128;
    const float* xd = dst_h + (size_t)dst_idx[e] * 128;
    float z0 = b2[0], z1 = b2[1];
    for (int j = 0; j < 128; ++j) {
        float s = b1[j];
        for (int k = 0; k < 128; ++k) s += xs[k] * W1[k * 128 + j];
        for (int k = 0; k < 128; ++k) s += xd[k] * W1[(128 + k) * 128 + j];
        float h = fmaxf(s, 0.f);
        z0 = fmaf(h, W2[j * 2], z0);
        z1 = fmaf(h, W2[j * 2 + 1], z1);
    }
    float p0 = 1.f / (1.f + __expf(z1 - z0));
    out[(size_t)e * 2] = p0; out[(size_t)e * 2 + 1] = 1.f - p0;
}

extern "C" void kernel_launch(void* const* d_in, const int* in_sizes, int n_in,
                              void* d_out, int out_size, void* d_ws, size_t ws_size,
                              hipStream_t stream) {
    const float* src_h   = (const float*)d_in[0];
    const float* dst_h   = (const float*)d_in[1];
    const int*   src_idx = (const int*)d_in[2];
    const int*   dst_idx = (const int*)d_in[3];
    const float* W1      = (const float*)d_in[4];
    const float* b1      = (const float*)d_in[5];
    const float* W2      = (const float*)d_in[6];
    const float* b2      = (const float*)d_in[7];
    float* out = (float*)d_out;

    int n_nodes = in_sizes[0] / 128;
    int n_edges = in_sizes[2];

    size_t tbl_shorts = (size_t)n_nodes * 256;               // P + Q
    size_t need = (tbl_shorts + 32768) * sizeof(short);      // + w1t_sw
    bool use_bf16 = (ws_size >= need);

    if (use_bf16) {
        short* ws     = (short*)d_ws;
        short* Pp     = ws;
        short* Qp     = ws + (size_t)n_nodes * 128;
        short* w1t_sw = ws + tbl_shorts;

        hipLaunchKernelGGL(convert_w1, dim3(16), dim3(256), 0, stream, W1, w1t_sw);

        int n_tiles = (n_nodes + 127) / 128;
        hipLaunchKernelGGL(precompute_pq, dim3(2 * n_tiles), dim3(256), 0, stream,
                           w1t_sw, b1, src_h, dst_h, Pp, Qp, n_nodes, n_tiles);

        int n_batches = (n_edges + 63) / 64;
        int grid = n_batches < 2048 ? n_batches : 2048;
        hipLaunchKernelGGL(edge_score, dim3(grid), dim3(256), 0, stream,
                           Pp, Qp, src_idx, dst_idx, W2, b2,
                           out, n_edges, n_batches);
    } else {
        hipLaunchKernelGGL(edge_naive, dim3((n_edges + 255) / 256), dim3(256), 0, stream,
                           src_h, dst_h, src_idx, dst_idx,
                           W1, b1, W2, b2, out, n_edges);
    }
}

// Round 5
// 114.042 us; speedup vs baseline: 2.0300x; 1.0800x over previous
//
#include <hip/hip_runtime.h>
#include <hip/hip_bf16.h>

typedef short bf16x8 __attribute__((ext_vector_type(8)));
typedef float f32x4  __attribute__((ext_vector_type(4)));
typedef float f32x16 __attribute__((ext_vector_type(16)));

__device__ inline short f2bf(float f) {
    __hip_bfloat16 h = __float2bfloat16(f);
    return *reinterpret_cast<short*>(&h);
}
__device__ inline float bf2f(short s) {
    union { unsigned u; float f; } x;
    x.u = (unsigned)(unsigned short)s << 16;
    return x.f;
}

// ------- pre-pass 1: W1 [256,128] f32 -> w1t_sw: two 32 KB halves, each in
// the EXACT swizzled LDS image precompute_pq uses ([col][chunk], byte
// offset cc*256 + ((ci*16) ^ ((cc&15)<<4))).
__global__ void __launch_bounds__(256) convert_w1(
    const float* __restrict__ W1, short* __restrict__ w1t_sw)
{
    int i = blockIdx.x * 256 + threadIdx.x;   // 4096 threads: (H, cc, ci)
    int H  = i >> 11;
    int r  = i & 2047;
    int cc = r >> 4, ci = r & 15;
    bf16x8 v;
    #pragma unroll
    for (int j = 0; j < 8; ++j)
        v[j] = f2bf(W1[(size_t)(H * 128 + ci * 8 + j) * 128 + cc]);
    char* base = reinterpret_cast<char*>(w1t_sw) + H * 32768;
    *reinterpret_cast<bf16x8*>(base + cc * 256 + ((ci * 16) ^ ((cc & 15) << 4))) = v;
}

// ------- pre-pass 2: P = src_h @ W1[:128] + b1, Q = dst_h @ W1[128:] ----
// Grid-strided, FILL-ONCE: block bb handles table tb = bb&1, tiles
// t = bb>>1, += gridDim/2. LDS fill = one linear 32 KB memcpy (L2-hot),
// done once per block, amortized over ~1.5 tiles. No barrier in the tile
// loop (sW read-only after fill). Round-3/4 post-mortem: per-tile blocks
// cost ~7 us vs fill-once grid-stride, independent of fill speed.
__global__ void __launch_bounds__(256) precompute_pq(
    const short* __restrict__ w1t_sw, const float* __restrict__ b1,
    const float* __restrict__ src_h, const float* __restrict__ dst_h,
    short* __restrict__ P, short* __restrict__ Q,
    int n_nodes, int n_tiles)
{
    __shared__ short sW[128 * 128];   // 32 KB: [col][16 chunks of 16B], XOR-swizzled

    const int bb   = blockIdx.x;
    const int tb   = bb & 1;          // 0 = src/P, 1 = dst/Q
    const int bt   = bb >> 1;         // block index within table
    const int nblk = gridDim.x >> 1;  // blocks per table
    const int tid  = threadIdx.x;

    {   // fill once: straight copy, 8 x b128 per thread, fully coalesced
        const short* src = w1t_sw + tb * 16384;
        #pragma unroll
        for (int ch = 0; ch < 8; ++ch) {
            int g = ch * 256 + tid;           // 0..2047 16B-chunks
            *reinterpret_cast<bf16x8*>(sW + (size_t)g * 8) =
                *reinterpret_cast<const bf16x8*>(src + (size_t)g * 8);
        }
    }
    __syncthreads();

    const int lane = tid & 63;
    const int wv   = tid >> 6;
    const int l31  = lane & 31;
    const int hg   = lane >> 5;

    const float* X = tb ? dst_h : src_h;
    short*       T = tb ? Q : P;

    // hoist per-lane b1 (folded into P only)
    float b1v[4];
    #pragma unroll
    for (int nf = 0; nf < 4; ++nf)
        b1v[nf] = tb ? 0.0f : b1[nf * 32 + l31];

    for (int t = bt; t < n_tiles; t += nblk) {
        const int nodeBase = t * 128 + wv * 32;
        if (nodeBase < n_nodes) {
            int nl = nodeBase + l31; if (nl >= n_nodes) nl = n_nodes - 1;
            const float* x = X + (size_t)nl * 128 + hg * 8;

            f32x16 acc[4];
            #pragma unroll
            for (int nf = 0; nf < 4; ++nf) acc[nf] = (f32x16)(0.0f);

            #pragma unroll
            for (int kk = 0; kk < 8; ++kk) {
                f32x4 u = *reinterpret_cast<const f32x4*>(x + kk * 16);
                f32x4 v = *reinterpret_cast<const f32x4*>(x + kk * 16 + 4);
                bf16x8 a;
                #pragma unroll
                for (int j = 0; j < 4; ++j) { a[j] = f2bf(u[j]); a[4 + j] = f2bf(v[j]); }
                #pragma unroll
                for (int nf = 0; nf < 4; ++nf) {
                    int col = nf * 32 + l31;
                    const char* bp = reinterpret_cast<const char*>(sW)
                        + col * 256 + ((kk * 32 + hg * 16) ^ ((col & 15) << 4));
                    bf16x8 bfr = *reinterpret_cast<const bf16x8*>(bp);
                    acc[nf] = __builtin_amdgcn_mfma_f32_32x32x16_bf16(a, bfr, acc[nf], 0, 0, 0);
                }
            }

            #pragma unroll
            for (int nf = 0; nf < 4; ++nf) {
                int col = nf * 32 + l31;
                #pragma unroll
                for (int rg = 0; rg < 16; ++rg) {
                    int row  = (rg & 3) + 8 * (rg >> 2) + 4 * hg;
                    int node = nodeBase + row;
                    if (node < n_nodes)
                        T[(size_t)node * 128 + col] = f2bf(acc[nf][rg] + b1v[nf]);
                }
            }
        }
    }
}

// ------- main: pure gather + elementwise.  16 lanes per node-row.
// Wave batch = 64 edges (4 iters x 16 edges, slots i=0..3, group g=lane>>4).
// Double-buffered row loads, idx prefetched 2 iters ahead, dense 512B stores.
// Service-rate bound at ~6.6 TB/s combined L2/L3 random-row service
// (round-3 A/B: 2x occupancy -> +4%). Grid sized for exactly 2 batches/wave
// (round-4 analysis: 2048-block grid ran its 2nd pass at 91% balance).
// NOTE: min-waves hint stays at 4. VGPR=60 <= 64 already allows 8 blocks/CU;
// forcing 8 squeezed VGPR to 32 and spilled the pipeline state to scratch
// (round-2 post-mortem: WRITE_SIZE 7.8 -> 209 MB, dur 79.5 -> 186 us).
__global__ void __launch_bounds__(256, 4) edge_score(
    const short* __restrict__ P, const short* __restrict__ Q,
    const int* __restrict__ src_idx, const int* __restrict__ dst_idx,
    const float* __restrict__ W2, const float* __restrict__ b2,
    float* __restrict__ out, int n_edges, int n_batches)
{
    __shared__ float sOut[4][128];       // per-wave 64 x float2 bounce

    const int tid  = threadIdx.x;
    const int wv   = tid >> 6;
    const int lane = tid & 63;
    const int g    = lane >> 4;          // 0..3  : edge slot-within-quad
    const int c    = lane & 15;          // 0..15 : 8-feature chunk of the row

    float* sOutW = &sOut[wv][0];

    // per-lane constants: this lane's 8 feature channels (b1 folded into P)
    float wdf[8];
    #pragma unroll
    for (int j = 0; j < 8; ++j) {
        int k = c * 8 + j;
        wdf[j] = W2[k * 2 + 1] - W2[k * 2 + 0];   // w2[:,1]-w2[:,0]
    }
    const float cdiff = b2[1] - b2[0];

    const int gw = blockIdx.x * 4 + wv;
    const int nw = gridDim.x * 4;

    for (int b = gw; b < n_batches; b += nw) {
        const int ebase = b << 6;

        int    is_[2][4], id_[2][4];
        bf16x8 pv_[2][4], qv_[2][4];

        // prologue: idx(0) -> rows(0) -> idx(1)
        #pragma unroll
        for (int i = 0; i < 4; ++i) {
            int e = ebase + i * 4 + g; if (e >= n_edges) e = n_edges - 1;
            is_[0][i] = src_idx[e]; id_[0][i] = dst_idx[e];
        }
        #pragma unroll
        for (int i = 0; i < 4; ++i) {
            pv_[0][i] = *reinterpret_cast<const bf16x8*>(P + (size_t)is_[0][i] * 128 + c * 8);
            qv_[0][i] = *reinterpret_cast<const bf16x8*>(Q + (size_t)id_[0][i] * 128 + c * 8);
        }
        #pragma unroll
        for (int i = 0; i < 4; ++i) {
            int e = ebase + 16 + i * 4 + g; if (e >= n_edges) e = n_edges - 1;
            is_[1][i] = src_idx[e]; id_[1][i] = dst_idx[e];
        }

        #pragma unroll
        for (int n = 0; n < 4; ++n) {
            const int cur = n & 1, nxt = cur ^ 1;

            // issue rows(n+1) from idx(n+1)
            if (n < 3) {
                #pragma unroll
                for (int i = 0; i < 4; ++i) {
                    pv_[nxt][i] = *reinterpret_cast<const bf16x8*>(P + (size_t)is_[nxt][i] * 128 + c * 8);
                    qv_[nxt][i] = *reinterpret_cast<const bf16x8*>(Q + (size_t)id_[nxt][i] * 128 + c * 8);
                }
            }
            // prefetch idx(n+2) into the just-freed slot
            if (n < 2) {
                #pragma unroll
                for (int i = 0; i < 4; ++i) {
                    int e = ebase + (n + 2) * 16 + i * 4 + g; if (e >= n_edges) e = n_edges - 1;
                    is_[cur][i] = src_idx[e]; id_[cur][i] = dst_idx[e];
                }
            }
            // compute(n)
            #pragma unroll
            for (int i = 0; i < 4; ++i) {
                float a = 0.f;
                #pragma unroll
                for (int j = 0; j < 8; ++j) {
                    float h = fmaxf(bf2f(pv_[cur][i][j]) + bf2f(qv_[cur][i][j]), 0.f);
                    a = fmaf(h, wdf[j], a);
                }
                a += __shfl_xor(a, 1);
                a += __shfl_xor(a, 2);
                a += __shfl_xor(a, 4);
                a += __shfl_xor(a, 8);
                if (c == i) {
                    float D  = a + cdiff;                      // z1 - z0
                    float p0 = 1.0f / (1.0f + __expf(D));
                    reinterpret_cast<float2*>(sOutW)[n * 16 + i * 4 + g] =
                        make_float2(p0, 1.0f - p0);
                }
            }
        }

        // dense full-wave store: 64 lanes x float2 = 512B contiguous
        asm volatile("s_waitcnt lgkmcnt(0)" ::: "memory");
        {
            float2 r = reinterpret_cast<float2*>(sOutW)[lane];
            int e = ebase + lane;
            if (e < n_edges)
                *reinterpret_cast<float2*>(out + (size_t)e * 2) = r;
        }
    }
}

// ------- fallback (ws too small; not expected to run) -------
__global__ void __launch_bounds__(256) edge_naive(
    const float* __restrict__ src_h, const float* __restrict__ dst_h,
    const int* __restrict__ src_idx, const int* __restrict__ dst_idx,
    const float* __restrict__ W1, const float* __restrict__ b1,
    const float* __restrict__ W2, const float* __restrict__ b2,
    float* __restrict__ out, int n_edges)
{
    int e = blockIdx.x * 256 + threadIdx.x;
    if (e >= n_edges) return;
    const float* xs = src_h + (size_t)src_idx[e] * 128;
    const float* xd = dst_h + (size_t)dst_idx[e] * 128;
    float z0 = b2[0], z1 = b2[1];
    for (int j = 0; j < 128; ++j) {
        float s = b1[j];
        for (int k = 0; k < 128; ++k) s += xs[k] * W1[k * 128 + j];
        for (int k = 0; k < 128; ++k) s += xd[k] * W1[(128 + k) * 128 + j];
        float h = fmaxf(s, 0.f);
        z0 = fmaf(h, W2[j * 2], z0);
        z1 = fmaf(h, W2[j * 2 + 1], z1);
    }
    float p0 = 1.f / (1.f + __expf(z1 - z0));
    out[(size_t)e * 2] = p0; out[(size_t)e * 2 + 1] = 1.f - p0;
}

extern "C" void kernel_launch(void* const* d_in, const int* in_sizes, int n_in,
                              void* d_out, int out_size, void* d_ws, size_t ws_size,
                              hipStream_t stream) {
    const float* src_h   = (const float*)d_in[0];
    const float* dst_h   = (const float*)d_in[1];
    const int*   src_idx = (const int*)d_in[2];
    const int*   dst_idx = (const int*)d_in[3];
    const float* W1      = (const float*)d_in[4];
    const float* b1      = (const float*)d_in[5];
    const float* W2      = (const float*)d_in[6];
    const float* b2      = (const float*)d_in[7];
    float* out = (float*)d_out;

    int n_nodes = in_sizes[0] / 128;
    int n_edges = in_sizes[2];

    size_t tbl_shorts = (size_t)n_nodes * 256;               // P + Q
    size_t need = (tbl_shorts + 32768) * sizeof(short);      // + w1t_sw
    bool use_bf16 = (ws_size >= need);

    if (use_bf16) {
        short* ws     = (short*)d_ws;
        short* Pp     = ws;
        short* Qp     = ws + (size_t)n_nodes * 128;
        short* w1t_sw = ws + tbl_shorts;

        hipLaunchKernelGGL(convert_w1, dim3(16), dim3(256), 0, stream, W1, w1t_sw);

        int n_tiles = (n_nodes + 127) / 128;
        int pre_grid = 2 * n_tiles < 1024 ? 2 * n_tiles : 1024;  // 512/table, 4/CU
        hipLaunchKernelGGL(precompute_pq, dim3(pre_grid), dim3(256), 0, stream,
                           w1t_sw, b1, src_h, dst_h, Pp, Qp, n_nodes, n_tiles);

        int n_batches = (n_edges + 63) / 64;
        int grid = (n_batches + 7) / 8;                      // exactly 2 batches/wave
        if (grid > 2048) grid = 2048;
        if (grid < 1) grid = 1;
        hipLaunchKernelGGL(edge_score, dim3(grid), dim3(256), 0, stream,
                           Pp, Qp, src_idx, dst_idx, W2, b2,
                           out, n_edges, n_batches);
    } else {
        hipLaunchKernelGGL(edge_naive, dim3((n_edges + 255) / 256), dim3(256), 0, stream,
                           src_h, dst_h, src_idx, dst_idx,
                           W1, b1, W2, b2, out, n_edges);
    }
}